// Round 10
// baseline (169.189 us; speedup 1.0000x reference)
//
#include <hip/hip_runtime.h>
#include <math.h>

// Problem constants
#define BATCH 256
#define IC    1152
#define EDIM  8
#define NC    10
#define DV    16

// Tiling
#define ITILE  8                    // i's covered by thread layout (il = 0..7)
#define NCHUNK 6                    // grid 24x64=1536 = exactly 6/CU (R9)
#define ITOT   (ITILE * NCHUNK)     // 48 i's per block
#define NB     4                    // b's per block (R7's NB=8 cost occupancy. KEEP 4)
#define NTHREADS 256                // 256 = 16 d * 2 il_lo * 2 ch * 4 il_hi
#define NWAVES 4
#define NSLAB  (IC / ITOT)          // 24 partial slabs
#define BCHUNKS (BATCH / NB)        // 64
#define SCD (NC * DV)               // 160
#define SPART_STRIDE (BATCH * SCD)  // 40960 floats per slab
#define L2E 1.4426950408889634f
#define XF4_TOT (NB * ITOT * EDIM / 4)   // 384 float4 of x per block
#define XF4_ROW (ITOT * EDIM / 4)        // 96 float4 per b row
#define WT_F4   (NSLAB * NCHUNK * NWAVES * 10 * 64)  // 368,640 float4 = 5.9 MB

typedef float v2f __attribute__((ext_vector_type(2)));
typedef float v4f __attribute__((ext_vector_type(4)));

// ---------------------------------------------------------------------------
// DPP-based 16-lane (row) sum reduce — all VALU, no DS pipe.
// MUST stay on __builtin_amdgcn_update_dpp: the compiler inserts the
// mandatory VALU->DPP hazard wait-states. R2's hand-written v_add_f32_dpp
// inline asm skipped them (hazard recognizer doesn't scan asm bodies) and
// silently read stale lanes -> absmax 0.39 FAIL. Do not regress.
// ---------------------------------------------------------------------------
template<int CTRL>
__device__ __forceinline__ float dpp_add(float x) {
    int r = __builtin_amdgcn_update_dpp(0, __float_as_int(x), CTRL, 0xF, 0xF, true);
    return x + __int_as_float(r);
}
__device__ __forceinline__ float row_reduce16(float x) {
    x = dpp_add<0xB1>(x);   // quad_perm [1,0,3,2] : xor 1
    x = dpp_add<0x4E>(x);   // quad_perm [2,3,0,1] : xor 2
    x = dpp_add<0x141>(x);  // row_half_mirror     : xor 4
    x = dpp_add<0x140>(x);  // row_mirror          : xor 8
    return x;
}

// ---------------------------------------------------------------------------
// Cross-half (lane ^ 32) sum, pure VALU on gfx950 (no DS pipe / lgkmcnt).
// r[0]+r[1] == x + partner(x) in every lane. Builtin — HW-verified in R1.
// ---------------------------------------------------------------------------
typedef int int2v __attribute__((ext_vector_type(2)));
#if __has_builtin(__builtin_amdgcn_permlane32_swap)
__device__ __forceinline__ float cross32_sum(float x) {
    int2v r = __builtin_amdgcn_permlane32_swap(__float_as_int(x), __float_as_int(x),
                                               false, false);
    return __int_as_float(r[0]) + __int_as_float(r[1]);
}
#else
__device__ __forceinline__ float cross32_sum(float x) { return x + __shfl_xor(x, 32); }
#endif

#if __has_builtin(__builtin_amdgcn_exp2f)
#define EXP2F(x) __builtin_amdgcn_exp2f(x)
#else
#define EXP2F(x) exp2f(x)
#endif

// ---------------------------------------------------------------------------
// 8-element fp32 dot via packed math: v_pk_fma_f32 (CDNA2+ 2xfp32).
// 1 pk_mul + 3 pk_fma + 1 add. R6-proven; dropped VGPR 84->68.
// ---------------------------------------------------------------------------
__device__ __forceinline__ float dot8_pk(v4f w0, v4f w1, v4f x0, v4f x1) {
    v2f a =  __builtin_shufflevector(w0, w0, 0, 1) * __builtin_shufflevector(x0, x0, 0, 1);
    a = __builtin_elementwise_fma(__builtin_shufflevector(w0, w0, 2, 3),
                                  __builtin_shufflevector(x0, x0, 2, 3), a);
    a = __builtin_elementwise_fma(__builtin_shufflevector(w1, w1, 0, 1),
                                  __builtin_shufflevector(x1, x1, 0, 1), a);
    a = __builtin_elementwise_fma(__builtin_shufflevector(w1, w1, 2, 3),
                                  __builtin_shufflevector(x1, x1, 2, 3), a);
    return a[0] + a[1];
}

// ---------------------------------------------------------------------------
// R10 pre-pass: transpose W into wave-fragment-major layout.
//   Wt[(icb*6+ic)*4+wid][k][h][lane]  (float4 granules)
// so each of the 10 chunk-head W loads in caps_main is 64 lanes x 16B
// FULLY CONTIGUOUS (1 segment, 8 granules, 100% line use) instead of the
// stride-2 pattern (4 segments, 16 granules, 50% line use) of the native
// [i][c][dv][e] layout. Runs once per launch: 5.9 MB move, ~4 us.
// ---------------------------------------------------------------------------
__global__ __launch_bounds__(256)
void caps_wxform(const float4* __restrict__ W4, float4* __restrict__ Wt)
{
    int o = blockIdx.x * 256 + threadIdx.x;          // 0 .. WT_F4-1
    int lane = o & 63;
    int h    = (o >> 6) & 1;
    int kk   = (o >> 7) % 5;
    int wc   = o / 640;                               // (icb*6+ic)*4+wid
    int wid  = wc & 3;
    int icic = wc >> 2;                               // icb*6+ic
    int ic   = icic % NCHUNK;
    int icb  = icic / NCHUNK;
    int d     = lane & 15;
    int il_lo = (lane >> 4) & 1;
    int ch    = (lane >> 5) & 1;
    int i = icb * ITOT + ic * ITILE + wid * 2 + il_lo;
    int c = ch * 5 + kk;
    Wt[o] = W4[((size_t)(i * NC + c) * DV + d) * 2 + h];
}

// ---------------------------------------------------------------------------
// Main fused kernel. LANE MAP: d = bits0-3, il_lo = bit4, ch = bit5,
// il_hi = bits6-7 (== wid). ch at bit5 makes the softmax cross-ch sum a
// v_permlane32_swap (VALU). il = il_lo + wid*2.
//
// BOTTLENECK MODEL (R0-R9): latency plateau at ~47-51us across all
// configs; mode-independent; VALU-busy time ~25us << wall; HBM 5-8%;
// conflicts 0. Remaining suspect matching mode-independence: W-load
// TRANSACTION SHAPE (stride-2, 50% granule use, 16 granules/instr).
// R10: W pre-transposed (caps_wxform) -> all 10 W loads per chunk are
// fully contiguous 1KB wave-loads. Register-neutral. REVERT/STOP if
// caps_main >= 50us (TA theory dead -> plateau is structural).
//
// Structural lessons (do not regress):
//   R1: device-atomic s-accum -> WRITE_SIZE 4x. REVERTED.
//   R2: inline-asm DPP skips hazard nops -> silent corruption. REVERTED.
//   R4: LDS-staging b2/bias: VGPR 88 -> occupancy cliff. REVERTED.
//   R5: grid(bcb-fast) W-sweep -> FETCH +17MB. Keep icb fast axis.
//   R7: NB=8 -> VGPR 116, 4 waves/SIMD, 70us. REVERTED.
//   R8: cross-chunk W prefetch -> VGPR 88, no gain at equal occ. REVERTED.
//
// NUMERICS: softmax max-pass removed (|logits| <~ 20 << 88; R1/R3-proven).
// 1/sum via v_rcp_f32 (rel err ~1e-7). Routing logits in log2 domain:
// v_in pre-scaled by L2E (caps_squash writes it), bias scaled once per
// i-chunk, so softmax exp is raw v_exp_f32 (exp2). b2 stores scaled
// logits (internal-only buffer, consistent between MODE 2 and 3).
//
// MODE 1: c = softmax(bias)                              -> s1 partials
// MODE 2: b2 = L2E*(u.v1) + 2*L2E*bias (stored), softmax -> s2 partials
// MODE 3: b3 = L2E*(u.v2) + b2 + L2E*bias, softmax       -> s3 partials
// ---------------------------------------------------------------------------
template<int MODE>
__global__ __launch_bounds__(NTHREADS, 2)
void caps_main(const float* __restrict__ x,
               const v4f* __restrict__ Wt,
               const float* __restrict__ bias,
               const float* __restrict__ v_in,   // pre-scaled by L2E
               float* __restrict__ b2,
               float* __restrict__ s_part)
{
    __shared__ float sx[NB][ITOT * EDIM];    // 6 KB
    __shared__ float swv[NWAVES][NB][SCD];   // 10 KB — wave-private slabs
    __shared__ float vls[NB][SCD];           // 2.5 KB — v tile (MODE != 1)

    const int tid = threadIdx.x;
    const int d   = tid & 15;
    const int ch  = (tid >> 5) & 1;                       // lane bit 5
    const int il  = ((tid >> 4) & 1) | (((tid >> 6) & 3) << 1);
    const int wid = tid >> 6;                // 0..3
    const int icb = blockIdx.x;              // 0..23  (fast axis — R5 lesson)
    const int bcb = blockIdx.y;              // 0..63
    const int i0  = icb * ITOT;
    const int b0  = bcb * NB;

    // ---- stage x slice: 384 float4, coalesced ----
    {
        const float4* xg = (const float4*)x;
        float4* xs = (float4*)&sx[0][0];
        #pragma unroll
        for (int t = 0; t < 2; ++t) {
            int idx = t * NTHREADS + tid;
            if (idx < XF4_TOT) {
                int bb = idx / XF4_ROW;
                int w  = idx - bb * XF4_ROW;
                xs[idx] = xg[(size_t)(b0 + bb) * (IC * EDIM / 4)
                             + i0 * (EDIM / 4) + w];
            }
        }
    }
    // ---- stage v tile (640 floats, coalesced) ----
    if (MODE != 1) {
        #pragma unroll
        for (int t = 0; t < 3; ++t) {
            int j = t * NTHREADS + tid;
            if (j < NB * SCD)
                (&vls[0][0])[j] = v_in[(size_t)b0 * SCD + j];
        }
    }

    float sacc[NB][5];
    #pragma unroll
    for (int bb = 0; bb < NB; ++bb)
        #pragma unroll
        for (int k = 0; k < 5; ++k) sacc[bb][k] = 0.f;

    __syncthreads();

    // per-wave Wt base for this block (chunk 0): lane-resolved
    const v4f* wpb = Wt + (size_t)((icb * NCHUNK) * NWAVES + wid) * 640
                        + (tid & 63);

    #pragma unroll 1
    for (int ic = 0; ic < NCHUNK; ++ic) {
        const int i = i0 + ic * ITILE + il;
        const v4f* wp = wpb + (size_t)ic * (NWAVES * 640);

        // W fragment (contiguous 1KB wave-loads) + bias for this i-chunk
        v4f   w4[5][2];
        float bv[5];
        #pragma unroll
        for (int k = 0; k < 5; ++k) {
            w4[k][0] = wp[(k * 2 + 0) * 64];
            w4[k][1] = wp[(k * 2 + 1) * 64];
            bv[k]    = bias[i * NC + ch * 5 + k];
        }

        float cw[5];
        float bvs[5];
        if (MODE == 1) {
            // softmax(bias[i,:]) — batch-independent, once per i-chunk
            float ssum = 0.f, ex[5];
            #pragma unroll
            for (int k = 0; k < 5; ++k) { ex[k] = __expf(bv[k]); ssum += ex[k]; }
            ssum = cross32_sum(ssum);
            float inv = __builtin_amdgcn_rcpf(ssum);
            #pragma unroll
            for (int k = 0; k < 5; ++k) cw[k] = ex[k] * inv;
        } else {
            #pragma unroll
            for (int k = 0; k < 5; ++k) bvs[k] = bv[k] * L2E;
        }

        #pragma unroll
        for (int bb = 0; bb < NB; ++bb) {
            const int b = b0 + bb;
            const v4f x0 = ((const v4f*)&sx[bb][(ic * ITILE + il) * EDIM])[0];
            const v4f x1 = ((const v4f*)&sx[bb][(ic * ITILE + il) * EDIM])[1];

            // u_hat[b, i, c_k, d] — packed-pair dot (v_pk_fma_f32)
            float u[5];
            #pragma unroll
            for (int k = 0; k < 5; ++k)
                u[k] = dot8_pk(w4[k][0], w4[k][1], x0, x1);

            if (MODE != 1) {
                // agreement (L2E-scaled via v): sum over d via DPP row reduce
                const float* vb = &vls[bb][ch * 80 + d];
                float t[5];
                #pragma unroll
                for (int k = 0; k < 5; ++k) t[k] = u[k] * vb[k * 16];
                #pragma unroll
                for (int k = 0; k < 5; ++k) t[k] = row_reduce16(t[k]);

                float br[5];
                float* bp = b2 + (((size_t)b * IC + i) * 2 + ch) * 8;  // padded
                if (MODE == 2) {
                    #pragma unroll
                    for (int k = 0; k < 5; ++k) br[k] = fmaf(2.0f, bvs[k], t[k]);
                    if (d == 0) {
                        #pragma unroll
                        for (int k = 0; k < 5; ++k) bp[k] = br[k];
                    }
                } else {
                    #pragma unroll
                    for (int k = 0; k < 5; ++k) br[k] = t[k] + bp[k] + bvs[k];
                }
                // softmax over 10 c's: 5 local + partner half via permlane32.
                // Logits are log2-domain -> raw v_exp_f32, no max-pass.
                float ssum = 0.f, ex[5];
                #pragma unroll
                for (int k = 0; k < 5; ++k) { ex[k] = EXP2F(br[k]); ssum += ex[k]; }
                ssum = cross32_sum(ssum);
                float inv = __builtin_amdgcn_rcpf(ssum);
                #pragma unroll
                for (int k = 0; k < 5; ++k) cw[k] = ex[k] * inv;
            }

            // register s-accumulation — no LDS, no shuffle, no barrier
            #pragma unroll
            for (int k = 0; k < 5; ++k)
                sacc[bb][k] = fmaf(cw[k], u[k], sacc[bb][k]);
        }
    }

    // ---- epilogue: il-pair reduce + wave slabs + 4-way reduce + flush ----
    #pragma unroll
    for (int bb = 0; bb < NB; ++bb) {
        #pragma unroll
        for (int k = 0; k < 5; ++k) {
            float s = sacc[bb][k] + __shfl_xor(sacc[bb][k], 16);
            if ((tid & 16) == 0)
                swv[wid][bb][ch * 80 + k * 16 + d] = s;
        }
    }
    __syncthreads();
    for (int j = tid; j < NB * SCD; j += NTHREADS) {    // 640 elems
        int bb = j / SCD;
        int cd = j - bb * SCD;
        float s = (swv[0][bb][cd] + swv[1][bb][cd])
                + (swv[2][bb][cd] + swv[3][bb][cd]);
        s_part[((size_t)icb * BATCH + b0 + bb) * SCD + cd] = s;
    }
}

// ---------------------------------------------------------------------------
// Reduce s-partials over the 24 slabs and apply squash.
// Block = 16 (b,c) groups x 16 d. Grid = 2560/16 = 160 blocks.
// mult = L2E for intermediate v (log2-domain routing), 1.0 for final out.
// ---------------------------------------------------------------------------
__global__ __launch_bounds__(256)
void caps_squash(const float* __restrict__ s_part, float* __restrict__ out,
                 float mult)
{
    const int tid = threadIdx.x;
    const int bc  = blockIdx.x * 16 + (tid >> 4);
    const size_t off = (size_t)bc * DV + (tid & 15);

    float a[4] = {0.f, 0.f, 0.f, 0.f};
    #pragma unroll
    for (int ic = 0; ic < NSLAB; ic += 4) {             // 24 = 6 x 4
        #pragma unroll
        for (int j = 0; j < 4; ++j)
            a[j] += s_part[(size_t)(ic + j) * SPART_STRIDE + off];
    }
    float s = (a[0] + a[1]) + (a[2] + a[3]);

    float sq = row_reduce16(s * s);

    // scale = sq/(1+sq)/sqrt(sq+EPS), EPS = 1e-7 (matches reference)
    float scale = sq / ((1.0f + sq) * sqrtf(sq + 1e-7f));
    out[off] = (mult * scale) * s;
}

// ---------------------------------------------------------------------------
extern "C" void kernel_launch(void* const* d_in, const int* in_sizes, int n_in,
                              void* d_out, int out_size, void* d_ws, size_t ws_size,
                              hipStream_t stream)
{
    const float* x    = (const float*)d_in[0];   // [256,1152,8]
    const float* W    = (const float*)d_in[1];   // [1152,10,16,8]
    const float* bias = (const float*)d_in[2];   // [1152,10]
    float* out = (float*)d_out;                  // [256,10,16]

    float* ws     = (float*)d_ws;
    float* s_part = ws;                                       // 24*40960 = 983,040 f
    float* v      = s_part + (size_t)NSLAB * SPART_STRIDE;    // 40,960 f (L2E-scaled)
    float* b2     = v + SPART_STRIDE;                         // padded: 4,718,592 f
    float* wt     = b2 + (size_t)BATCH * IC * 16;             // 1,474,560 f (5.9 MB)
    // total ws use: ~29 MB

    // icb on the FAST grid axis (R5 lesson). With NSLAB=24, all 64 blocks
    // sharing an icb land on the same XCD (R9): per-XCD W locality.
    dim3 grid(NSLAB, BCHUNKS);   // 24 x 64 = 1536 blocks = 6 per CU exactly

    // W layout transform (once per launch, ~4 us)
    caps_wxform<<<WT_F4 / 256, 256, 0, stream>>>((const float4*)W, (float4*)wt);

    // iter 1
    caps_main<1><<<grid, NTHREADS, 0, stream>>>(x, (const v4f*)wt, bias, v, b2, s_part);
    caps_squash<<<160, 256, 0, stream>>>(s_part, v, L2E);
    // iter 2
    caps_main<2><<<grid, NTHREADS, 0, stream>>>(x, (const v4f*)wt, bias, v, b2, s_part);
    caps_squash<<<160, 256, 0, stream>>>(s_part, v, L2E);
    // final
    caps_main<3><<<grid, NTHREADS, 0, stream>>>(x, (const v4f*)wt, bias, v, b2, s_part);
    caps_squash<<<160, 256, 0, stream>>>(s_part, out, 1.0f);
}

// Round 11
// 163.369 us; speedup vs baseline: 1.0356x; 1.0356x over previous
//
#include <hip/hip_runtime.h>
#include <math.h>

// Problem constants
#define BATCH 256
#define IC    1152
#define EDIM  8
#define NC    10
#define DV    16

// Tiling
#define ITILE  8                    // i's covered by thread layout (il = 0..7)
#define NCHUNK 6                    // grid 24x64=1536 = exactly 6/CU (R9)
#define ITOT   (ITILE * NCHUNK)     // 48 i's per block
#define NB     4                    // b's per block (R7's NB=8 cost occupancy. KEEP 4)
#define NTHREADS 256                // 256 = 16 d * 2 il_lo * 2 ch * 4 il_hi
#define NWAVES 4
#define NSLAB  (IC / ITOT)          // 24 partial slabs
#define BCHUNKS (BATCH / NB)        // 64
#define SCD (NC * DV)               // 160
#define SPART_STRIDE (BATCH * SCD)  // 40960 floats per slab
#define L2E 1.4426950408889634f
#define XF4_TOT (NB * ITOT * EDIM / 4)   // 384 float4 of x per block
#define XF4_ROW (ITOT * EDIM / 4)        // 96 float4 per b row
#define WXU     2560                      // float4 per (icb,ic) unit
#define WT_F4   (NSLAB * NCHUNK * WXU)    // 368,640 float4 = 5.9 MB

typedef float v2f __attribute__((ext_vector_type(2)));
typedef float v4f __attribute__((ext_vector_type(4)));

// ---------------------------------------------------------------------------
// DPP-based 16-lane (row) sum reduce — all VALU, no DS pipe.
// MUST stay on __builtin_amdgcn_update_dpp: the compiler inserts the
// mandatory VALU->DPP hazard wait-states. R2's hand-written v_add_f32_dpp
// inline asm skipped them (hazard recognizer doesn't scan asm bodies) and
// silently read stale lanes -> absmax 0.39 FAIL. Do not regress.
// ---------------------------------------------------------------------------
template<int CTRL>
__device__ __forceinline__ float dpp_add(float x) {
    int r = __builtin_amdgcn_update_dpp(0, __float_as_int(x), CTRL, 0xF, 0xF, true);
    return x + __int_as_float(r);
}
__device__ __forceinline__ float row_reduce16(float x) {
    x = dpp_add<0xB1>(x);   // quad_perm [1,0,3,2] : xor 1
    x = dpp_add<0x4E>(x);   // quad_perm [2,3,0,1] : xor 2
    x = dpp_add<0x141>(x);  // row_half_mirror     : xor 4
    x = dpp_add<0x140>(x);  // row_mirror          : xor 8
    return x;
}

// ---------------------------------------------------------------------------
// Cross-half (lane ^ 32) sum, pure VALU on gfx950 (no DS pipe / lgkmcnt).
// r[0]+r[1] == x + partner(x) in every lane. Builtin — HW-verified in R1.
// ---------------------------------------------------------------------------
typedef int int2v __attribute__((ext_vector_type(2)));
#if __has_builtin(__builtin_amdgcn_permlane32_swap)
__device__ __forceinline__ float cross32_sum(float x) {
    int2v r = __builtin_amdgcn_permlane32_swap(__float_as_int(x), __float_as_int(x),
                                               false, false);
    return __int_as_float(r[0]) + __int_as_float(r[1]);
}
#else
__device__ __forceinline__ float cross32_sum(float x) { return x + __shfl_xor(x, 32); }
#endif

#if __has_builtin(__builtin_amdgcn_exp2f)
#define EXP2F(x) __builtin_amdgcn_exp2f(x)
#else
#define EXP2F(x) exp2f(x)
#endif

// ---------------------------------------------------------------------------
// 8-element fp32 dot via packed math: v_pk_fma_f32 (CDNA2+ 2xfp32).
// 1 pk_mul + 3 pk_fma + 1 add. R6-proven; dropped VGPR 84->68.
// ---------------------------------------------------------------------------
__device__ __forceinline__ float dot8_pk(v4f w0, v4f w1, v4f x0, v4f x1) {
    v2f a =  __builtin_shufflevector(w0, w0, 0, 1) * __builtin_shufflevector(x0, x0, 0, 1);
    a = __builtin_elementwise_fma(__builtin_shufflevector(w0, w0, 2, 3),
                                  __builtin_shufflevector(x0, x0, 2, 3), a);
    a = __builtin_elementwise_fma(__builtin_shufflevector(w1, w1, 0, 1),
                                  __builtin_shufflevector(x1, x1, 0, 1), a);
    a = __builtin_elementwise_fma(__builtin_shufflevector(w1, w1, 2, 3),
                                  __builtin_shufflevector(x1, x1, 2, 3), a);
    return a[0] + a[1];
}

// ---------------------------------------------------------------------------
// R11 pre-pass: W -> wave-fragment-major Wt, LDS-TILED so BOTH global
// streams are perfectly coalesced (R10's gather version confirmed the
// transposed layout wins -15% in caps_main, but its stride-2 16B reads
// cost ~15-20us and ate the gain).
//
// Key observation: for one (icb,ic) unit, source (8 i's x 320 f4) and
// destination (4 wids x 640 f4) are BOTH fully contiguous 2560-f4 spans.
// One block per unit: read 2560 f4 coalesced -> 40KB LDS -> permuted
// write 2560 f4 coalesced. 11.8 MB total => ~2-3us.
//
// Permutation (float4 units, verified against R10's gather mapping):
//   src  li = il*320 + c*32 + d*2 + h
//   dst  lo = wid*640 + kk*128 + h*64 + ch*32 + il_lo*16 + d
//   with il = wid*2+il_lo, c = ch*5+kk.
// ---------------------------------------------------------------------------
__global__ __launch_bounds__(256)
void caps_wxform(const float4* __restrict__ W4, float4* __restrict__ Wt)
{
    __shared__ float4 lds[WXU];              // 40 KB
    const int tid = threadIdx.x;
    const size_t base = (size_t)blockIdx.x * WXU;   // unit = icb*6+ic

    #pragma unroll
    for (int t = 0; t < WXU / 256; ++t)
        lds[t * 256 + tid] = W4[base + t * 256 + tid];
    __syncthreads();
    #pragma unroll
    for (int t = 0; t < WXU / 256; ++t) {
        int lo   = t * 256 + tid;
        int wid  = lo / 640;
        int r0   = lo - wid * 640;
        int kk   = r0 >> 7;                  // 0..4
        int r1   = r0 & 127;
        int h    = r1 >> 6;
        int ch   = (r1 >> 5) & 1;
        int il_lo= (r1 >> 4) & 1;
        int d    = r1 & 15;
        int il   = wid * 2 + il_lo;
        int c    = ch * 5 + kk;
        Wt[base + lo] = lds[il * 320 + c * 32 + d * 2 + h];
    }
}

// ---------------------------------------------------------------------------
// Main fused kernel. LANE MAP: d = bits0-3, il_lo = bit4, ch = bit5,
// il_hi = bits6-7 (== wid). ch at bit5 makes the softmax cross-ch sum a
// v_permlane32_swap (VALU). il = il_lo + wid*2.
//
// BOTTLENECK MODEL (R0-R10): the ~47-51us plateau was part W-load
// TRANSACTION SHAPE: with wave-contiguous Wt loads (1KB/instr, 100% line
// use) caps_main = 43.9us, VGPR 72 (R10 CONFIRMED). R10's net-neutral
// total was the naive gather pre-pass giving the win back; R11 fixes the
// pre-pass, not this kernel.
//
// Structural lessons (do not regress):
//   R1: device-atomic s-accum -> WRITE_SIZE 4x. REVERTED.
//   R2: inline-asm DPP skips hazard nops -> silent corruption. REVERTED.
//   R4: LDS-staging b2/bias: VGPR 88 -> occupancy cliff. REVERTED.
//   R5: grid(bcb-fast) W-sweep -> FETCH +17MB. Keep icb fast axis.
//   R7: NB=8 -> VGPR 116, 4 waves/SIMD, 70us. REVERTED.
//   R8: cross-chunk W prefetch -> VGPR 88, no gain at equal occ. REVERTED.
//   R10: transposed W layout GOOD (-7.5us/dispatch); gather pre-pass BAD.
//
// NUMERICS: softmax max-pass removed (|logits| <~ 20 << 88; R1/R3-proven).
// 1/sum via v_rcp_f32 (rel err ~1e-7). Routing logits in log2 domain:
// v_in pre-scaled by L2E (caps_squash writes it), bias scaled once per
// i-chunk, so softmax exp is raw v_exp_f32 (exp2). b2 stores scaled
// logits (internal-only buffer, consistent between MODE 2 and 3).
//
// MODE 1: c = softmax(bias)                              -> s1 partials
// MODE 2: b2 = L2E*(u.v1) + 2*L2E*bias (stored), softmax -> s2 partials
// MODE 3: b3 = L2E*(u.v2) + b2 + L2E*bias, softmax       -> s3 partials
// ---------------------------------------------------------------------------
template<int MODE>
__global__ __launch_bounds__(NTHREADS, 2)
void caps_main(const float* __restrict__ x,
               const v4f* __restrict__ Wt,
               const float* __restrict__ bias,
               const float* __restrict__ v_in,   // pre-scaled by L2E
               float* __restrict__ b2,
               float* __restrict__ s_part)
{
    __shared__ float sx[NB][ITOT * EDIM];    // 6 KB
    __shared__ float swv[NWAVES][NB][SCD];   // 10 KB — wave-private slabs
    __shared__ float vls[NB][SCD];           // 2.5 KB — v tile (MODE != 1)

    const int tid = threadIdx.x;
    const int d   = tid & 15;
    const int ch  = (tid >> 5) & 1;                       // lane bit 5
    const int il  = ((tid >> 4) & 1) | (((tid >> 6) & 3) << 1);
    const int wid = tid >> 6;                // 0..3
    const int icb = blockIdx.x;              // 0..23  (fast axis — R5 lesson)
    const int bcb = blockIdx.y;              // 0..63
    const int i0  = icb * ITOT;
    const int b0  = bcb * NB;

    // ---- stage x slice: 384 float4, coalesced ----
    {
        const float4* xg = (const float4*)x;
        float4* xs = (float4*)&sx[0][0];
        #pragma unroll
        for (int t = 0; t < 2; ++t) {
            int idx = t * NTHREADS + tid;
            if (idx < XF4_TOT) {
                int bb = idx / XF4_ROW;
                int w  = idx - bb * XF4_ROW;
                xs[idx] = xg[(size_t)(b0 + bb) * (IC * EDIM / 4)
                             + i0 * (EDIM / 4) + w];
            }
        }
    }
    // ---- stage v tile (640 floats, coalesced) ----
    if (MODE != 1) {
        #pragma unroll
        for (int t = 0; t < 3; ++t) {
            int j = t * NTHREADS + tid;
            if (j < NB * SCD)
                (&vls[0][0])[j] = v_in[(size_t)b0 * SCD + j];
        }
    }

    float sacc[NB][5];
    #pragma unroll
    for (int bb = 0; bb < NB; ++bb)
        #pragma unroll
        for (int k = 0; k < 5; ++k) sacc[bb][k] = 0.f;

    __syncthreads();

    // per-wave Wt base for this block (chunk 0): lane-resolved
    const v4f* wpb = Wt + (size_t)((icb * NCHUNK) * NWAVES + wid) * 640
                        + (tid & 63);

    #pragma unroll 1
    for (int ic = 0; ic < NCHUNK; ++ic) {
        const int i = i0 + ic * ITILE + il;
        const v4f* wp = wpb + (size_t)ic * (NWAVES * 640);

        // W fragment (contiguous 1KB wave-loads) + bias for this i-chunk
        v4f   w4[5][2];
        float bv[5];
        #pragma unroll
        for (int k = 0; k < 5; ++k) {
            w4[k][0] = wp[(k * 2 + 0) * 64];
            w4[k][1] = wp[(k * 2 + 1) * 64];
            bv[k]    = bias[i * NC + ch * 5 + k];
        }

        float cw[5];
        float bvs[5];
        if (MODE == 1) {
            // softmax(bias[i,:]) — batch-independent, once per i-chunk
            float ssum = 0.f, ex[5];
            #pragma unroll
            for (int k = 0; k < 5; ++k) { ex[k] = __expf(bv[k]); ssum += ex[k]; }
            ssum = cross32_sum(ssum);
            float inv = __builtin_amdgcn_rcpf(ssum);
            #pragma unroll
            for (int k = 0; k < 5; ++k) cw[k] = ex[k] * inv;
        } else {
            #pragma unroll
            for (int k = 0; k < 5; ++k) bvs[k] = bv[k] * L2E;
        }

        #pragma unroll
        for (int bb = 0; bb < NB; ++bb) {
            const int b = b0 + bb;
            const v4f x0 = ((const v4f*)&sx[bb][(ic * ITILE + il) * EDIM])[0];
            const v4f x1 = ((const v4f*)&sx[bb][(ic * ITILE + il) * EDIM])[1];

            // u_hat[b, i, c_k, d] — packed-pair dot (v_pk_fma_f32)
            float u[5];
            #pragma unroll
            for (int k = 0; k < 5; ++k)
                u[k] = dot8_pk(w4[k][0], w4[k][1], x0, x1);

            if (MODE != 1) {
                // agreement (L2E-scaled via v): sum over d via DPP row reduce
                const float* vb = &vls[bb][ch * 80 + d];
                float t[5];
                #pragma unroll
                for (int k = 0; k < 5; ++k) t[k] = u[k] * vb[k * 16];
                #pragma unroll
                for (int k = 0; k < 5; ++k) t[k] = row_reduce16(t[k]);

                float br[5];
                float* bp = b2 + (((size_t)b * IC + i) * 2 + ch) * 8;  // padded
                if (MODE == 2) {
                    #pragma unroll
                    for (int k = 0; k < 5; ++k) br[k] = fmaf(2.0f, bvs[k], t[k]);
                    if (d == 0) {
                        #pragma unroll
                        for (int k = 0; k < 5; ++k) bp[k] = br[k];
                    }
                } else {
                    #pragma unroll
                    for (int k = 0; k < 5; ++k) br[k] = t[k] + bp[k] + bvs[k];
                }
                // softmax over 10 c's: 5 local + partner half via permlane32.
                // Logits are log2-domain -> raw v_exp_f32, no max-pass.
                float ssum = 0.f, ex[5];
                #pragma unroll
                for (int k = 0; k < 5; ++k) { ex[k] = EXP2F(br[k]); ssum += ex[k]; }
                ssum = cross32_sum(ssum);
                float inv = __builtin_amdgcn_rcpf(ssum);
                #pragma unroll
                for (int k = 0; k < 5; ++k) cw[k] = ex[k] * inv;
            }

            // register s-accumulation — no LDS, no shuffle, no barrier
            #pragma unroll
            for (int k = 0; k < 5; ++k)
                sacc[bb][k] = fmaf(cw[k], u[k], sacc[bb][k]);
        }
    }

    // ---- epilogue: il-pair reduce + wave slabs + 4-way reduce + flush ----
    #pragma unroll
    for (int bb = 0; bb < NB; ++bb) {
        #pragma unroll
        for (int k = 0; k < 5; ++k) {
            float s = sacc[bb][k] + __shfl_xor(sacc[bb][k], 16);
            if ((tid & 16) == 0)
                swv[wid][bb][ch * 80 + k * 16 + d] = s;
        }
    }
    __syncthreads();
    for (int j = tid; j < NB * SCD; j += NTHREADS) {    // 640 elems
        int bb = j / SCD;
        int cd = j - bb * SCD;
        float s = (swv[0][bb][cd] + swv[1][bb][cd])
                + (swv[2][bb][cd] + swv[3][bb][cd]);
        s_part[((size_t)icb * BATCH + b0 + bb) * SCD + cd] = s;
    }
}

// ---------------------------------------------------------------------------
// Reduce s-partials over the 24 slabs and apply squash.
// Block = 16 (b,c) groups x 16 d. Grid = 2560/16 = 160 blocks.
// mult = L2E for intermediate v (log2-domain routing), 1.0 for final out.
// ---------------------------------------------------------------------------
__global__ __launch_bounds__(256)
void caps_squash(const float* __restrict__ s_part, float* __restrict__ out,
                 float mult)
{
    const int tid = threadIdx.x;
    const int bc  = blockIdx.x * 16 + (tid >> 4);
    const size_t off = (size_t)bc * DV + (tid & 15);

    float a[4] = {0.f, 0.f, 0.f, 0.f};
    #pragma unroll
    for (int ic = 0; ic < NSLAB; ic += 4) {             // 24 = 6 x 4
        #pragma unroll
        for (int j = 0; j < 4; ++j)
            a[j] += s_part[(size_t)(ic + j) * SPART_STRIDE + off];
    }
    float s = (a[0] + a[1]) + (a[2] + a[3]);

    float sq = row_reduce16(s * s);

    // scale = sq/(1+sq)/sqrt(sq+EPS), EPS = 1e-7 (matches reference)
    float scale = sq / ((1.0f + sq) * sqrtf(sq + 1e-7f));
    out[off] = (mult * scale) * s;
}

// ---------------------------------------------------------------------------
extern "C" void kernel_launch(void* const* d_in, const int* in_sizes, int n_in,
                              void* d_out, int out_size, void* d_ws, size_t ws_size,
                              hipStream_t stream)
{
    const float* x    = (const float*)d_in[0];   // [256,1152,8]
    const float* W    = (const float*)d_in[1];   // [1152,10,16,8]
    const float* bias = (const float*)d_in[2];   // [1152,10]
    float* out = (float*)d_out;                  // [256,10,16]

    float* ws     = (float*)d_ws;
    float* s_part = ws;                                       // 24*40960 = 983,040 f
    float* v      = s_part + (size_t)NSLAB * SPART_STRIDE;    // 40,960 f (L2E-scaled)
    float* b2     = v + SPART_STRIDE;                         // padded: 4,718,592 f
    float* wt     = b2 + (size_t)BATCH * IC * 16;             // 1,474,560 f (5.9 MB)
    // total ws use: ~29 MB

    // icb on the FAST grid axis (R5 lesson). With NSLAB=24, all 64 blocks
    // sharing an icb land on the same XCD (R9): per-XCD W locality.
    dim3 grid(NSLAB, BCHUNKS);   // 24 x 64 = 1536 blocks = 6 per CU exactly

    // W layout transform: LDS-tiled, both streams coalesced (~2-3 us)
    caps_wxform<<<NSLAB * NCHUNK, 256, 0, stream>>>((const float4*)W, (float4*)wt);

    // iter 1
    caps_main<1><<<grid, NTHREADS, 0, stream>>>(x, (const v4f*)wt, bias, v, b2, s_part);
    caps_squash<<<160, 256, 0, stream>>>(s_part, v, L2E);
    // iter 2
    caps_main<2><<<grid, NTHREADS, 0, stream>>>(x, (const v4f*)wt, bias, v, b2, s_part);
    caps_squash<<<160, 256, 0, stream>>>(s_part, v, L2E);
    // final
    caps_main<3><<<grid, NTHREADS, 0, stream>>>(x, (const v4f*)wt, bias, v, b2, s_part);
    caps_squash<<<160, 256, 0, stream>>>(s_part, out, 1.0f);
}